// Round 6
// baseline (106.180 us; speedup 1.0000x reference)
//
#include <hip/hip_runtime.h>
#include <math.h>

#define NB      25200
#define NB2     12600         // NB/2
#define NB4     6300          // NB/4
#define NBINS   512
#define CAP     256
#define MAXOUT  100
#define CONF    0.25f
#define IOU_T   0.45f
#define GRID2   64            // k_main blocks
#define THR2    256           // k_main threads
#define ITEMS_FB 100          // fallback: 256*100 = 25600 >= NB
#define NWAVE2  (THR2/64)

typedef unsigned long long u64;
typedef unsigned int u32;

__device__ __forceinline__ bool better(float sa_, int ia_, float sb_, int ib_) {
    return (sb_ > sa_) || (sb_ == sa_ && ib_ < ia_);
}

// ---------------- K1: histogram + threshold + zero-init of cnt/ticket ----------------
// ws_i layout: [0]=tbin  [1]=total_conf  [2]=cnt  [3]=ticket
__global__ __launch_bounds__(1024, 1)
void k_prep(const float* __restrict__ scores, int* __restrict__ ws_i)
{
    const int tid = threadIdx.x, lane = tid & 63;
    __shared__ int hist[NBINS];
    if (tid < NBINS) hist[tid] = 0;
    __syncthreads();

    const float4* s4 = (const float4*)scores;
    const float binscale = (float)NBINS / (1.0f - CONF);
#pragma unroll
    for (int k = 0; k < 7; ++k) {
        const int v = k * 1024 + tid;
        if (v < NB4) {
            const float4 s = s4[v];
            const float el[4] = {s.x, s.y, s.z, s.w};
#pragma unroll
            for (int e = 0; e < 4; ++e) {
                if (el[e] > CONF) {
                    int b = (int)((el[e] - CONF) * binscale);
                    b = b < 0 ? 0 : (b > NBINS - 1 ? NBINS - 1 : b);
                    atomicAdd(&hist[b], 1);
                }
            }
        }
    }
    __syncthreads();

    if (tid < 64) {                                  // wave 0: suffix scan + threshold
        int h[8];
#pragma unroll
        for (int r = 0; r < 8; ++r) h[r] = hist[lane * 8 + r];
        int ls[8]; int acc = 0;
#pragma unroll
        for (int r = 7; r >= 0; --r) { acc += h[r]; ls[r] = acc; }
        u32 inc = (u32)acc;                          // inclusive suffix over lane chunks
#pragma unroll
        for (int off = 1; off < 64; off <<= 1) {
            const u32 t = __shfl_down(inc, off);
            if (lane + off < 64) inc += t;
        }
        const int excl = (int)inc - acc;
        int loc = NBINS;                             // smallest bin with suffix <= CAP
#pragma unroll
        for (int r = 7; r >= 0; --r) { if (ls[r] + excl <= CAP) loc = lane * 8 + r; }
#pragma unroll
        for (int off = 32; off >= 1; off >>= 1) {
            const int t = __shfl_xor(loc, off);
            if (t < loc) loc = t;
        }
        const int total = (int)__shfl(inc, 0);       // total above CONF
        if (lane == 0) {
            ws_i[0] = loc; ws_i[1] = total; ws_i[2] = 0; ws_i[3] = 0;
        }
    }
}

// ---------------- K2: compact slices + last-block NMS ----------------
__global__ __launch_bounds__(THR2, 1)
void k_main(const float* __restrict__ boxes, const float* __restrict__ scores,
            int* __restrict__ ws_i, float* __restrict__ cand_s,
            int* __restrict__ cand_i, float4* __restrict__ cand_b,
            float* __restrict__ out)
{
    const int tid  = threadIdx.x;
    const int lane = tid & 63;
    const int wv   = tid >> 6;
    const int gtid = blockIdx.x * THR2 + tid;

    __shared__ u64    keys[CAP];
    __shared__ float4 sb[CAP];
    __shared__ float  ss[CAP];
    __shared__ float  sa[CAP];
    __shared__ u64    mat[CAP][4];
    __shared__ int    klist[MAXOUT];
    __shared__ int    s_kept, s_last;
    __shared__ float  red_v[NWAVE2];
    __shared__ int    red_i[NWAVE2];
    __shared__ float  live[25600];       // fallback only (100 KB)

    const float4* b4 = (const float4*)boxes;
    const float binscale = (float)NBINS / (1.0f - CONF);
    const int tbin = ws_i[0];            // written by k_prep (prev dispatch)

    // ---- compact this block's slice (2 scores/thread, float2) ----
    float2 sv = make_float2(-1.f, -1.f);
    if (gtid < NB2) sv = ((const float2*)scores)[gtid];
#pragma unroll
    for (int e = 0; e < 2; ++e) {
        const float s = e ? sv.y : sv.x;
        bool pred = false;
        if (s > CONF) {
            int b = (int)((s - CONF) * binscale);
            b = b < 0 ? 0 : (b > NBINS - 1 ? NBINS - 1 : b);
            pred = (b >= tbin);
        }
        const u64 m = __ballot(pred);
        if (m) {
            const int ldr = __ffsll(m) - 1;
            int base = 0;
            if (lane == ldr) base = atomicAdd(&ws_i[2], __popcll(m));
            base = __shfl(base, ldr);
            if (pred) {
                const int pos = base + __popcll(m & ((1ull << lane) - 1ull));
                if (pos < CAP) {
                    const int i = 2 * gtid + e;
                    cand_s[pos] = s; cand_i[pos] = i; cand_b[pos] = b4[i];
                }
            }
        }
    }

    // ---- last-arriving block proceeds (release/acquire via ticket) ----
    __syncthreads();                      // drains this block's stores (vmcnt before barrier)
    if (tid == 0) {
        __threadfence();                  // release: L2 writeback, device scope
        const int old = atomicAdd(&ws_i[3], 1);
        s_last = (old == (int)gridDim.x - 1);
    }
    __syncthreads();
    if (!s_last) return;
    __threadfence();                      // acquire: invalidate, see all blocks' writes

    const int M0 = ws_i[2];
    const int total_conf = ws_i[1];
    const int M  = (M0 > CAP) ? CAP : M0;

    // ---- B1: sort keys (score desc, orig idx asc); sentinels larger than any real key ----
    float  cs = 0.f; int ci = 0; float4 cb = make_float4(0.f, 0.f, 0.f, 0.f);
    if (tid < M) { cs = cand_s[tid]; ci = cand_i[tid]; cb = cand_b[tid]; }
    keys[tid] = (tid < M)
        ? (((u64)(~__float_as_uint(cs)) << 32) | (u64)(u32)ci)
        : (0xFFFFFFFF00000000ULL | (u64)tid);
    __syncthreads();

    // ---- B2: rank by counting (broadcast LDS reads), scatter into sorted order ----
    {
        const u64 mykey = keys[tid];
        int rank = 0;
#pragma unroll 8
        for (int j = 0; j < CAP; ++j) rank += (keys[j] < mykey) ? 1 : 0;
        if (tid < M) {
            sb[rank] = cb;
            ss[rank] = cs;
            sa[rank] = fmaxf(cb.z - cb.x, 0.f) * fmaxf(cb.w - cb.y, 0.f);
        }
    }
    __syncthreads();

    // ---- B4: suppression bitmatrix, j > i only ----
#pragma unroll
    for (int q = 0; q < 4; ++q) {
        const int task = q * THR2 + tid;
        const int i = task >> 2;
        const int w = task & 3;
        u64 bits = 0ULL;
        if (i < M) {
            const float4 bi = sb[i];
            const float  ai = sa[i];
            const int base = w << 6;
            int j0 = i + 1 - base; if (j0 < 0) j0 = 0;
            int j1 = M - base;     if (j1 > 64) j1 = 64;
            for (int jj = j0; jj < j1; ++jj) {
                const float4 bj = sb[base + jj];
                const float ltx = fmaxf(bi.x, bj.x);
                const float lty = fmaxf(bi.y, bj.y);
                const float rbx = fminf(bi.z, bj.z);
                const float rby = fminf(bi.w, bj.w);
                const float w_ = fmaxf(rbx - ltx, 0.f);
                const float h_ = fmaxf(rby - lty, 0.f);
                const float inter = w_ * h_;
                const float den = ((ai + sa[base + jj]) - inter) + 1e-9f;  // ref assoc order
                if (inter > IOU_T * den) bits |= (1ULL << jj);
            }
        }
        mat[i][w] = bits;
    }
    __syncthreads();

    // ---- B5: serial greedy scan, 8-row prefetch groups ----
    if (tid == 0) {
        u64 r0 = 0, r1 = 0, r2 = 0, r3 = 0;
        int kept = 0;
        for (int base = 0; base < M && kept < MAXOUT; base += 8) {
            u64 rw[8][4];
#pragma unroll
            for (int q = 0; q < 8; ++q)
#pragma unroll
                for (int w = 0; w < 4; ++w) rw[q][w] = mat[base + q][w];
#pragma unroll
            for (int q = 0; q < 8; ++q) {
                const int i = base + q;
                if (i >= M || kept >= MAXOUT) break;
                const int w = i >> 6, b = i & 63;
                const u64 cur = (w == 0) ? r0 : (w == 1) ? r1 : (w == 2) ? r2 : r3;
                if (!((cur >> b) & 1ULL)) {
                    klist[kept++] = i;
                    if (kept == MAXOUT) break;
                    r0 |= rw[q][0]; r1 |= rw[q][1]; r2 |= rw[q][2]; r3 |= rw[q][3];
                }
            }
        }
        s_kept = kept;
    }
    __syncthreads();

    const int kept = s_kept;
    const bool need_fb = (M0 > CAP) || (kept < MAXOUT && M0 < total_conf);
    if (!need_fb) {                                   // uniform branch
        if (tid < MAXOUT) {
            float4 bb = make_float4(0.f, 0.f, 0.f, 0.f);
            float  sc_ = 0.f;
            if (tid < kept) { const int j = klist[tid]; bb = sb[j]; sc_ = ss[j]; }
            out[4*tid+0] = bb.x; out[4*tid+1] = bb.y;
            out[4*tid+2] = bb.z; out[4*tid+3] = bb.w;
            out[4*MAXOUT + tid] = sc_;
        }
        return;
    }

    // ---------------- exact full fallback (never on bench data) ----------------
    for (int k = 0; k < ITEMS_FB; ++k) {
        const int i = k * THR2 + tid;
        float sc0 = -INFINITY;
        if (i < NB) { const float s0 = scores[i]; sc0 = (s0 > CONF) ? s0 : -INFINITY; }
        live[i] = sc0;
    }
    __syncthreads();
    for (int r = 0; r < MAXOUT; ++r) {
        float lm = -INFINITY; int li = 0x7fffffff;
        for (int k = 0; k < ITEMS_FB; ++k) {
            const int i = k * THR2 + tid;
            const float v = live[i];
            if (v > lm) { lm = v; li = i; }           // ascending scan: ties -> lower i
        }
        float rv = lm; int ri = li;
#pragma unroll
        for (int off = 32; off >= 1; off >>= 1) {
            const float ov = __shfl_xor(rv, off);
            const int   oi = __shfl_xor(ri, off);
            if (better(rv, ri, ov, oi)) { rv = ov; ri = oi; }
        }
        __syncthreads();
        if (lane == 0) { red_v[wv] = rv; red_i[wv] = ri; }
        __syncthreads();
        float wval = red_v[0]; int widx = red_i[0];
#pragma unroll
        for (int j = 1; j < NWAVE2; ++j) {
            const float v = red_v[j]; const int i2 = red_i[j];
            if (better(wval, widx, v, i2)) { wval = v; widx = i2; }
        }
        if (!(wval > -1e38f)) {
            if (tid == 0) {
                out[4*r+0]=0.f; out[4*r+1]=0.f; out[4*r+2]=0.f; out[4*r+3]=0.f;
                out[4*MAXOUT + r] = 0.f;
            }
            continue;
        }
        const float4 wb = b4[widx];
        if (tid == 0) {
            out[4*r+0]=wb.x; out[4*r+1]=wb.y; out[4*r+2]=wb.z; out[4*r+3]=wb.w;
            out[4*MAXOUT + r] = wval;
        }
        const float warea = fmaxf(wb.z - wb.x, 0.f) * fmaxf(wb.w - wb.y, 0.f);
        for (int k = 0; k < ITEMS_FB; ++k) {
            const int i = k * THR2 + tid;
            if (i < NB) {
                const float4 bb = b4[i];
                const float area = fmaxf(bb.z - bb.x, 0.f) * fmaxf(bb.w - bb.y, 0.f);
                const float ltx = fmaxf(bb.x, wb.x);
                const float lty = fmaxf(bb.y, wb.y);
                const float rbx = fminf(bb.z, wb.z);
                const float rby = fminf(bb.w, wb.w);
                const float w  = fmaxf(rbx - ltx, 0.f);
                const float h  = fmaxf(rby - lty, 0.f);
                const float inter = w * h;
                const float den = ((warea + area) - inter) + 1e-9f;
                if (inter > IOU_T * den || i == widx) live[i] = -INFINITY;
            }
        }
        __syncthreads();
    }
}

extern "C" void kernel_launch(void* const* d_in, const int* in_sizes, int n_in,
                              void* d_out, int out_size, void* d_ws, size_t ws_size,
                              hipStream_t stream) {
    const float* boxes  = (const float*)d_in[0];
    const float* scores = (const float*)d_in[1];
    float* out = (float*)d_out;
    char* ws = (char*)d_ws;
    int*    ws_i   = (int*)ws;               // [0,16): tbin, total, cnt, ticket
    float4* cand_b = (float4*)(ws + 64);     // [64, 4160)  16B-aligned
    float*  cand_s = (float*)(ws + 4160);    // [4160, 5184)
    int*    cand_i = (int*)(ws + 5184);      // [5184, 6208)

    k_prep<<<dim3(1),     dim3(1024), 0, stream>>>(scores, ws_i);
    k_main<<<dim3(GRID2), dim3(THR2), 0, stream>>>(boxes, scores, ws_i,
                                                   cand_s, cand_i, cand_b, out);
}

// Round 7
// 93.215 us; speedup vs baseline: 1.1391x; 1.1391x over previous
//
#include <hip/hip_runtime.h>
#include <math.h>

#define NB      25200
#define NB4     6300          // NB/4 exactly
#define THREADS 1024
#define KV      7             // 7*1024 float4 = 28672 elems >= 25200
#define NBINS   512
#define CAP     256
#define MAXOUT  100
#define CONF    0.25f
#define IOU_T   0.45f
#define NWAVE   16
#define ITEMS_FB 25           // fallback: 1024*25 = 25600 >= NB

typedef unsigned long long u64;
typedef unsigned int u32;

__device__ __forceinline__ bool better(float sa_, int ia_, float sb_, int ib_) {
    return (sb_ > sa_) || (sb_ == sa_ && ib_ < ib_ * 0 + ia_);  // placeholder avoided below
}

__device__ __forceinline__ bool better2(float sa_, int ia_, float sb_, int ib_) {
    return (sb_ > sa_) || (sb_ == sa_ && ib_ < ia_);
}

__global__ __launch_bounds__(THREADS, 1)
void nms_all(const float* __restrict__ boxes,
             const float* __restrict__ scores,
             float* __restrict__ out)
{
    const int tid  = threadIdx.x;
    const int lane = tid & 63;
    const int wv   = tid >> 6;

    __shared__ int    hist[NBINS];
    __shared__ u64    keys[CAP];
    __shared__ float4 sbv[CAP];
    __shared__ float  ss[CAP];
    __shared__ float4 cand_b[CAP];
    __shared__ float  cand_s[CAP];
    __shared__ int    cand_i[CAP];
    __shared__ u64    mat[CAP][4];       // suppression bits, j > i only
    __shared__ int    prank[4][CAP];
    __shared__ int    klist[MAXOUT];
    __shared__ int    s_cnt, s_tbin, s_total, s_kept;
    __shared__ float  red_v[NWAVE];
    __shared__ int    red_i[NWAVE];
    __shared__ float  live[25600];       // fallback only (100 KB)

    const float4* b4 = (const float4*)boxes;
    const float4* s4 = (const float4*)scores;
    const float binscale = (float)NBINS / (1.0f - CONF);

    // ---- A0: issue all score loads first (28 regs/thread), then init LDS ----
    float4 sc[KV];
#pragma unroll
    for (int k = 0; k < KV; ++k) {
        const int v = k * THREADS + tid;
        sc[k] = (v < NB4) ? s4[v] : make_float4(-1.f, -1.f, -1.f, -1.f);
    }
    if (tid < NBINS) hist[tid] = 0;
    if (tid == 0) s_cnt = 0;
    __syncthreads();

    // ---- A1: histogram from registers ----
#pragma unroll
    for (int k = 0; k < KV; ++k) {
        const float el[4] = {sc[k].x, sc[k].y, sc[k].z, sc[k].w};
#pragma unroll
        for (int e = 0; e < 4; ++e) {
            if (el[e] > CONF) {
                int b = (int)((el[e] - CONF) * binscale);
                b = b < 0 ? 0 : (b > NBINS - 1 ? NBINS - 1 : b);
                atomicAdd(&hist[b], 1);
            }
        }
    }
    __syncthreads();

    // ---- A2: wave-0 suffix scan -> threshold bin ----
    if (tid < 64) {
        int h[8], ls[8];
#pragma unroll
        for (int r = 0; r < 8; ++r) h[r] = hist[lane * 8 + r];
        int acc = 0;
#pragma unroll
        for (int r = 7; r >= 0; --r) { acc += h[r]; ls[r] = acc; }
        u32 inc = (u32)acc;                       // inclusive suffix over lane chunks
#pragma unroll
        for (int off = 1; off < 64; off <<= 1) {
            const u32 t = __shfl_down(inc, off);
            if (lane + off < 64) inc += t;
        }
        const int excl = (int)inc - acc;
        int loc = NBINS;                          // smallest bin with suffix <= CAP
#pragma unroll
        for (int r = 7; r >= 0; --r) { if (ls[r] + excl <= CAP) loc = lane * 8 + r; }
#pragma unroll
        for (int off = 32; off >= 1; off >>= 1) {
            const int t = __shfl_xor(loc, off);
            if (t < loc) loc = t;
        }
        const int total = (int)__shfl(inc, 0);
        if (lane == 0) { s_tbin = loc; s_total = total; }
    }
    __syncthreads();
    const int tbin       = s_tbin;                // NBINS -> nothing selected -> fallback
    const int total_conf = s_total;

    // ---- A3: ballot compaction (bin >= tbin), LDS counter ----
#pragma unroll
    for (int k = 0; k < KV; ++k) {
        const int v = k * THREADS + tid;
        const float el[4] = {sc[k].x, sc[k].y, sc[k].z, sc[k].w};
#pragma unroll
        for (int e = 0; e < 4; ++e) {
            const float s = el[e];
            bool pred = false;
            if (s > CONF) {
                int b = (int)((s - CONF) * binscale);
                b = b < 0 ? 0 : (b > NBINS - 1 ? NBINS - 1 : b);
                pred = (b >= tbin);
            }
            const u64 m = __ballot(pred);
            if (m) {
                const int ldr = __ffsll(m) - 1;
                int base = 0;
                if (lane == ldr) base = atomicAdd(&s_cnt, __popcll(m));
                base = __shfl(base, ldr);
                if (pred) {
                    const int pos = base + __popcll(m & ((1ull << lane) - 1ull));
                    if (pos < CAP) {
                        const int i = 4 * v + e;
                        cand_s[pos] = s; cand_i[pos] = i; cand_b[pos] = b4[i];
                    }
                }
            }
        }
    }
    __syncthreads();
    const int M0 = s_cnt;
    const int M  = (M0 > CAP) ? CAP : M0;

    // ---- B1: sort keys (score desc, orig idx asc); sentinels above all real keys ----
    float cs = 0.f; int ci = 0; float4 cb = make_float4(0.f, 0.f, 0.f, 0.f);
    if (tid < CAP) {
        if (tid < M) { cs = cand_s[tid]; ci = cand_i[tid]; cb = cand_b[tid]; }
        keys[tid] = (tid < M)
            ? (((u64)(~__float_as_uint(cs)) << 32) | (u64)(u32)ci)
            : (0xFFFFFFFF00000000ULL | (u64)tid);
    }
    __syncthreads();

    // ---- B2: rank by counting, 4 chunks x 256 keys, 16-deep batched loads ----
    {
        const int key   = tid & (CAP - 1);
        const int chunk = tid >> 8;               // 0..3
        const u64 myk   = keys[key];
        const int jb    = chunk * 64;
        int r = 0;
        for (int j0 = 0; j0 < 64; j0 += 16) {
            u64 kb[16];
#pragma unroll
            for (int q = 0; q < 16; ++q) kb[q] = keys[jb + j0 + q];   // broadcast reads
#pragma unroll
            for (int q = 0; q < 16; ++q) r += (kb[q] < myk) ? 1 : 0;
        }
        prank[chunk][key] = r;
    }
    __syncthreads();
    if (tid < CAP && tid < M) {
        const int rank = prank[0][tid] + prank[1][tid] + prank[2][tid] + prank[3][tid];
        sbv[rank] = cb;
        ss[rank]  = cs;
    }
    __syncthreads();

    // ---- B4: ballot-row bitmatrix. wave -> (word, 64-row range); columns in registers ----
    {
        const int word = wv & 3;
        const int rb   = (wv >> 2) * 64;
        const int jidx = (word << 6) + lane;
        const float4 bj = sbv[jidx];              // one b128 per wave; garbage if >= M (masked)
        const float  aj = fmaxf(bj.z - bj.x, 0.f) * fmaxf(bj.w - bj.y, 0.f);
        const bool   jv = (jidx < M);
        for (int ii = 0; ii < 64; ii += 4) {
            float4 bi[4];
#pragma unroll
            for (int q = 0; q < 4; ++q) bi[q] = sbv[rb + ii + q];     // broadcast, 4 in flight
#pragma unroll
            for (int q = 0; q < 4; ++q) {
                const int irow = rb + ii + q;
                const float ai = fmaxf(bi[q].z - bi[q].x, 0.f) * fmaxf(bi[q].w - bi[q].y, 0.f);
                const float ltx = fmaxf(bi[q].x, bj.x);
                const float lty = fmaxf(bi[q].y, bj.y);
                const float rbx = fminf(bi[q].z, bj.z);
                const float rby = fminf(bi[q].w, bj.w);
                const float w_ = fmaxf(rbx - ltx, 0.f);
                const float h_ = fmaxf(rby - lty, 0.f);
                const float inter = w_ * h_;
                const float den = ((ai + aj) - inter) + 1e-9f;        // ref assoc order
                const bool pred = jv && (irow < M) && (jidx > irow) && (inter > IOU_T * den);
                const u64 bal = __ballot(pred);
                if (lane == 0) mat[irow][word] = bal;
            }
        }
    }
    __syncthreads();

    // ---- B5: serial greedy scan, 8-row prefetch groups ----
    if (tid == 0) {
        u64 r0 = 0, r1 = 0, r2 = 0, r3 = 0;
        int kept = 0;
        for (int base = 0; base < M && kept < MAXOUT; base += 8) {
            u64 rw[8][4];
#pragma unroll
            for (int q = 0; q < 8; ++q)
#pragma unroll
                for (int w = 0; w < 4; ++w) rw[q][w] = mat[base + q][w];
#pragma unroll
            for (int q = 0; q < 8; ++q) {
                const int i = base + q;
                if (i >= M || kept >= MAXOUT) break;
                const int w = i >> 6, b = i & 63;
                const u64 cur = (w == 0) ? r0 : (w == 1) ? r1 : (w == 2) ? r2 : r3;
                if (!((cur >> b) & 1ULL)) {
                    klist[kept++] = i;
                    if (kept == MAXOUT) break;
                    r0 |= rw[q][0]; r1 |= rw[q][1]; r2 |= rw[q][2]; r3 |= rw[q][3];
                }
            }
        }
        s_kept = kept;
    }
    __syncthreads();

    // ---- epilogue / fallback decision ----
    const int kept = s_kept;
    const bool need_fb = (M0 > CAP) || (kept < MAXOUT && M0 < total_conf);
    if (!need_fb) {                                   // block-uniform branch
        if (tid < MAXOUT) {
            float4 bb = make_float4(0.f, 0.f, 0.f, 0.f);
            float  sc_ = 0.f;
            if (tid < kept) { const int j = klist[tid]; bb = sbv[j]; sc_ = ss[j]; }
            out[4*tid+0] = bb.x; out[4*tid+1] = bb.y;
            out[4*tid+2] = bb.z; out[4*tid+3] = bb.w;
            out[4*MAXOUT + tid] = sc_;
        }
        return;
    }

    // ---------------- exact full fallback (never on bench data) ----------------
    if (tid < 25600 - NB) live[NB + tid] = -INFINITY;
    for (int k = 0; k < ITEMS_FB; ++k) {
        const int i = k * THREADS + tid;
        if (i < NB) {
            const float s0 = scores[i];               // cold re-read; keeps sc[] range short
            live[i] = (s0 > CONF) ? s0 : -INFINITY;
        }
    }
    __syncthreads();
    for (int r = 0; r < MAXOUT; ++r) {
        float lm = -INFINITY; int li = 0x7fffffff;
        for (int k = 0; k < ITEMS_FB; ++k) {
            const int i = k * THREADS + tid;
            const float v = live[i];
            if (v > lm) { lm = v; li = i; }           // ascending scan: ties -> lower i
        }
        float rv = lm; int ri = li;
#pragma unroll
        for (int off = 32; off >= 1; off >>= 1) {
            const float ov = __shfl_xor(rv, off);
            const int   oi = __shfl_xor(ri, off);
            if (better2(rv, ri, ov, oi)) { rv = ov; ri = oi; }
        }
        __syncthreads();
        if (lane == 0) { red_v[wv] = rv; red_i[wv] = ri; }
        __syncthreads();
        float wval = red_v[0]; int widx = red_i[0];
#pragma unroll
        for (int j = 1; j < NWAVE; ++j) {
            const float v = red_v[j]; const int i2 = red_i[j];
            if (better2(wval, widx, v, i2)) { wval = v; widx = i2; }
        }
        if (!(wval > -1e38f)) {
            if (tid == 0) {
                out[4*r+0]=0.f; out[4*r+1]=0.f; out[4*r+2]=0.f; out[4*r+3]=0.f;
                out[4*MAXOUT + r] = 0.f;
            }
            continue;
        }
        const float4 wb = b4[widx];
        if (tid == 0) {
            out[4*r+0]=wb.x; out[4*r+1]=wb.y; out[4*r+2]=wb.z; out[4*r+3]=wb.w;
            out[4*MAXOUT + r] = wval;
        }
        const float warea = fmaxf(wb.z - wb.x, 0.f) * fmaxf(wb.w - wb.y, 0.f);
        for (int k = 0; k < ITEMS_FB; ++k) {
            const int i = k * THREADS + tid;
            if (i < NB) {
                const float4 bb = b4[i];
                const float area = fmaxf(bb.z - bb.x, 0.f) * fmaxf(bb.w - bb.y, 0.f);
                const float ltx = fmaxf(bb.x, wb.x);
                const float lty = fmaxf(bb.y, wb.y);
                const float rbx = fminf(bb.z, wb.z);
                const float rby = fminf(bb.w, wb.w);
                const float w  = fmaxf(rbx - ltx, 0.f);
                const float h  = fmaxf(rby - lty, 0.f);
                const float inter = w * h;
                const float den = ((warea + area) - inter) + 1e-9f;
                if (inter > IOU_T * den || i == widx) live[i] = -INFINITY;
            }
        }
        __syncthreads();
    }
}

extern "C" void kernel_launch(void* const* d_in, const int* in_sizes, int n_in,
                              void* d_out, int out_size, void* d_ws, size_t ws_size,
                              hipStream_t stream) {
    const float* boxes  = (const float*)d_in[0];
    const float* scores = (const float*)d_in[1];
    float* out = (float*)d_out;
    nms_all<<<dim3(1), dim3(THREADS), 0, stream>>>(boxes, scores, out);
}

// Round 8
// 77.194 us; speedup vs baseline: 1.3755x; 1.2075x over previous
//
#include <hip/hip_runtime.h>
#include <math.h>

#define NB      25200
#define NB4     6300          // NB/4 exactly
#define THREADS 1024
#define KV      7             // 7*1024 float4 = 28672 elems >= 25200
#define NBINS   512
#define CAP     128
#define MAXOUT  100
#define CONF    0.25f
#define PRE     0.98f         // pre-filter: only scores > PRE enter the histogram
#define IOU_T   0.45f
#define NWAVE   16
#define ITEMS_FB 25           // fallback: 1024*25 = 25600 >= NB

typedef unsigned long long u64;
typedef unsigned int u32;

__device__ __forceinline__ bool better(float sa_, int ia_, float sb_, int ib_) {
    return (sb_ > sa_) || (sb_ == sa_ && ib_ < ia_);
}

__global__ __launch_bounds__(THREADS, 1)
void nms_all(const float* __restrict__ boxes,
             const float* __restrict__ scores,
             float* __restrict__ out)
{
    const int tid  = threadIdx.x;
    const int lane = tid & 63;
    const int wv   = tid >> 6;

    __shared__ int    hist[NBINS];
    __shared__ u64    keys[CAP];
    __shared__ float4 sbv[CAP];
    __shared__ float  ss[CAP];
    __shared__ float4 cand_b[CAP];
    __shared__ float  cand_s[CAP];
    __shared__ int    cand_i[CAP];
    __shared__ u64    mat[CAP][2];       // suppression bits (128 cols), j > i only
    __shared__ int    prank[8][CAP];
    __shared__ int    klist[MAXOUT];
    __shared__ int    s_cnt, s_tbin, s_pack, s_kept;
    __shared__ float  red_v[NWAVE];
    __shared__ int    red_i[NWAVE];
    __shared__ float  live[25600];       // fallback only (100 KB)

    const float4* b4 = (const float4*)boxes;
    const float4* s4 = (const float4*)scores;
    const float binscale = (float)NBINS / (1.0f - PRE);

    // ---- A0: issue all score loads first (28 regs/thread), then init LDS ----
    float4 sc[KV];
#pragma unroll
    for (int k = 0; k < KV; ++k) {
        const int v = k * THREADS + tid;
        sc[k] = (v < NB4) ? s4[v] : make_float4(-1.f, -1.f, -1.f, -1.f);
    }
    if (tid < NBINS) hist[tid] = 0;
    if (tid == 0) { s_cnt = 0; s_pack = 0; }
    __syncthreads();

    // ---- A1: register counting; LDS atomics only for the ~2% above PRE ----
    int pack = 0;                        // (count>CONF)<<16 | (count>PRE)
#pragma unroll
    for (int k = 0; k < KV; ++k) {
        const float el[4] = {sc[k].x, sc[k].y, sc[k].z, sc[k].w};
#pragma unroll
        for (int e = 0; e < 4; ++e) {
            const float s = el[e];
            if (s > CONF) pack += 0x10000;
            if (s > PRE) {
                pack += 1;
                int b = (int)((s - PRE) * binscale);
                b = b < 0 ? 0 : (b > NBINS - 1 ? NBINS - 1 : b);
                atomicAdd(&hist[b], 1);
            }
        }
    }
#pragma unroll
    for (int off = 1; off < 64; off <<= 1) pack += __shfl_xor(pack, off);
    if (lane == 0) atomicAdd(&s_pack, pack);
    __syncthreads();
    const int total_conf = s_pack >> 16;

    // ---- A2: wave-0 suffix scan over 512 bins -> threshold bin ----
    if (tid < 64) {
        int h[8], ls[8];
#pragma unroll
        for (int r = 0; r < 8; ++r) h[r] = hist[lane * 8 + r];
        int acc = 0;
#pragma unroll
        for (int r = 7; r >= 0; --r) { acc += h[r]; ls[r] = acc; }
        u32 inc = (u32)acc;              // inclusive suffix over lane chunks
#pragma unroll
        for (int off = 1; off < 64; off <<= 1) {
            const u32 t = __shfl_down(inc, off);
            if (lane + off < 64) inc += t;
        }
        const int excl = (int)inc - acc;
        int loc = NBINS;                 // smallest bin with suffix <= CAP
#pragma unroll
        for (int r = 7; r >= 0; --r) { if (ls[r] + excl <= CAP) loc = lane * 8 + r; }
#pragma unroll
        for (int off = 32; off >= 1; off >>= 1) {
            const int t = __shfl_xor(loc, off);
            if (t < loc) loc = t;
        }
        if (lane == 0) s_tbin = loc;
    }
    __syncthreads();
    const int tbin = s_tbin;             // NBINS -> nothing selected -> fallback path

    // ---- A3: compaction; per-lane +1 atomics (compiler mbcnt-coalesces) ----
#pragma unroll
    for (int k = 0; k < KV; ++k) {
        const int v = k * THREADS + tid;
        const float el[4] = {sc[k].x, sc[k].y, sc[k].z, sc[k].w};
#pragma unroll
        for (int e = 0; e < 4; ++e) {
            const float s = el[e];
            bool pred = false;
            if (s > PRE) {
                int b = (int)((s - PRE) * binscale);
                b = b < 0 ? 0 : (b > NBINS - 1 ? NBINS - 1 : b);
                pred = (b >= tbin);
            }
            if (pred) {
                const int pos = atomicAdd(&s_cnt, 1);
                if (pos < CAP) {
                    const int i = 4 * v + e;
                    cand_s[pos] = s; cand_i[pos] = i; cand_b[pos] = b4[i];
                }
            }
        }
    }
    __syncthreads();
    const int M0 = s_cnt;
    const int M  = (M0 > CAP) ? CAP : M0;

    // ---- B1: sort keys (score desc, orig idx asc); sentinels above all real keys ----
    float cs = 0.f; int ci = 0; float4 cb = make_float4(0.f, 0.f, 0.f, 0.f);
    if (tid < CAP) {
        if (tid < M) { cs = cand_s[tid]; ci = cand_i[tid]; cb = cand_b[tid]; }
        keys[tid] = (tid < M)
            ? (((u64)(~__float_as_uint(cs)) << 32) | (u64)(u32)ci)
            : (0xFFFFFFFF00000000ULL | (u64)tid);
    }
    __syncthreads();

    // ---- B2: rank by counting, 8 chunks x 16 keys, batched broadcast loads ----
    {
        const int key   = tid & (CAP - 1);
        const int chunk = tid >> 7;      // 0..7
        const u64 myk   = keys[key];
        u64 kb[16];
#pragma unroll
        for (int q = 0; q < 16; ++q) kb[q] = keys[chunk * 16 + q];
        int r = 0;
#pragma unroll
        for (int q = 0; q < 16; ++q) r += (kb[q] < myk) ? 1 : 0;
        prank[chunk][key] = r;
    }
    __syncthreads();
    if (tid < CAP && tid < M) {
        int rank = 0;
#pragma unroll
        for (int c = 0; c < 8; ++c) rank += prank[c][tid];
        sbv[rank] = cb;
        ss[rank]  = cs;
    }
    __syncthreads();

    // ---- B4: ballot-row bitmatrix; 16 waves = 2 words x 8 row-groups of 16 ----
    {
        const int word = wv & 1;
        const int rb   = (wv >> 1) * 16;
        const int jidx = (word << 6) + lane;
        const float4 bj = sbv[jidx];     // one read; garbage if >= M (pred-masked)
        const float  aj = fmaxf(bj.z - bj.x, 0.f) * fmaxf(bj.w - bj.y, 0.f);
        const bool   jv = (jidx < M);
        for (int ii = 0; ii < 16; ii += 4) {
            float4 bi[4];
#pragma unroll
            for (int q = 0; q < 4; ++q) bi[q] = sbv[rb + ii + q];   // broadcast, 4 in flight
#pragma unroll
            for (int q = 0; q < 4; ++q) {
                const int irow = rb + ii + q;
                const float ai = fmaxf(bi[q].z - bi[q].x, 0.f) * fmaxf(bi[q].w - bi[q].y, 0.f);
                const float ltx = fmaxf(bi[q].x, bj.x);
                const float lty = fmaxf(bi[q].y, bj.y);
                const float rbx = fminf(bi[q].z, bj.z);
                const float rby = fminf(bi[q].w, bj.w);
                const float w_ = fmaxf(rbx - ltx, 0.f);
                const float h_ = fmaxf(rby - lty, 0.f);
                const float inter = w_ * h_;
                const float den = ((ai + aj) - inter) + 1e-9f;      // ref assoc order
                const bool pred = jv && (irow < M) && (jidx > irow) && (inter > IOU_T * den);
                const u64 bal = __ballot(pred);
                if (lane == 0) mat[irow][word] = bal;               // all 128x2 words written
            }
        }
    }
    __syncthreads();

    // ---- B5: serial greedy scan; rows are 16B -> one b128 each, 8-row prefetch ----
    if (tid == 0) {
        u64 r0 = 0, r1 = 0;
        int kept = 0;
        for (int base = 0; base < M && kept < MAXOUT; base += 8) {
            u64 rw[8][2];
#pragma unroll
            for (int q = 0; q < 8; ++q) { rw[q][0] = mat[base + q][0]; rw[q][1] = mat[base + q][1]; }
#pragma unroll
            for (int q = 0; q < 8; ++q) {
                const int i = base + q;
                if (i >= M || kept >= MAXOUT) break;
                const u64 cur = (i < 64) ? r0 : r1;
                if (!((cur >> (i & 63)) & 1ULL)) {
                    klist[kept++] = i;
                    if (kept == MAXOUT) break;
                    r0 |= rw[q][0]; r1 |= rw[q][1];
                }
            }
        }
        s_kept = kept;
    }
    __syncthreads();

    // ---- epilogue / fallback decision ----
    const int kept = s_kept;
    const bool need_fb = (M0 > CAP) || (kept < MAXOUT && M0 < total_conf);
    if (!need_fb) {                                   // block-uniform branch
        if (tid < MAXOUT) {
            float4 bb = make_float4(0.f, 0.f, 0.f, 0.f);
            float  sc_ = 0.f;
            if (tid < kept) { const int j = klist[tid]; bb = sbv[j]; sc_ = ss[j]; }
            out[4*tid+0] = bb.x; out[4*tid+1] = bb.y;
            out[4*tid+2] = bb.z; out[4*tid+3] = bb.w;
            out[4*MAXOUT + tid] = sc_;
        }
        return;
    }

    // ---------------- exact full fallback (never on bench data) ----------------
    if (tid < 25600 - NB) live[NB + tid] = -INFINITY;
    for (int k = 0; k < ITEMS_FB; ++k) {
        const int i = k * THREADS + tid;
        if (i < NB) {
            const float s0 = scores[i];
            live[i] = (s0 > CONF) ? s0 : -INFINITY;
        }
    }
    __syncthreads();
    for (int r = 0; r < MAXOUT; ++r) {
        float lm = -INFINITY; int li = 0x7fffffff;
        for (int k = 0; k < ITEMS_FB; ++k) {
            const int i = k * THREADS + tid;
            const float v = live[i];
            if (v > lm) { lm = v; li = i; }           // ascending scan: ties -> lower i
        }
        float rv = lm; int ri = li;
#pragma unroll
        for (int off = 32; off >= 1; off >>= 1) {
            const float ov = __shfl_xor(rv, off);
            const int   oi = __shfl_xor(ri, off);
            if (better(rv, ri, ov, oi)) { rv = ov; ri = oi; }
        }
        __syncthreads();
        if (lane == 0) { red_v[wv] = rv; red_i[wv] = ri; }
        __syncthreads();
        float wval = red_v[0]; int widx = red_i[0];
#pragma unroll
        for (int j = 1; j < NWAVE; ++j) {
            const float v = red_v[j]; const int i2 = red_i[j];
            if (better(wval, widx, v, i2)) { wval = v; widx = i2; }
        }
        if (!(wval > -1e38f)) {
            if (tid == 0) {
                out[4*r+0]=0.f; out[4*r+1]=0.f; out[4*r+2]=0.f; out[4*r+3]=0.f;
                out[4*MAXOUT + r] = 0.f;
            }
            continue;
        }
        const float4 wb = b4[widx];
        if (tid == 0) {
            out[4*r+0]=wb.x; out[4*r+1]=wb.y; out[4*r+2]=wb.z; out[4*r+3]=wb.w;
            out[4*MAXOUT + r] = wval;
        }
        const float warea = fmaxf(wb.z - wb.x, 0.f) * fmaxf(wb.w - wb.y, 0.f);
        for (int k = 0; k < ITEMS_FB; ++k) {
            const int i = k * THREADS + tid;
            if (i < NB) {
                const float4 bb = b4[i];
                const float area = fmaxf(bb.z - bb.x, 0.f) * fmaxf(bb.w - bb.y, 0.f);
                const float ltx = fmaxf(bb.x, wb.x);
                const float lty = fmaxf(bb.y, wb.y);
                const float rbx = fminf(bb.z, wb.z);
                const float rby = fminf(bb.w, wb.w);
                const float w  = fmaxf(rbx - ltx, 0.f);
                const float h  = fmaxf(rby - lty, 0.f);
                const float inter = w * h;
                const float den = ((warea + area) - inter) + 1e-9f;
                if (inter > IOU_T * den || i == widx) live[i] = -INFINITY;
            }
        }
        __syncthreads();
    }
}

extern "C" void kernel_launch(void* const* d_in, const int* in_sizes, int n_in,
                              void* d_out, int out_size, void* d_ws, size_t ws_size,
                              hipStream_t stream) {
    const float* boxes  = (const float*)d_in[0];
    const float* scores = (const float*)d_in[1];
    float* out = (float*)d_out;
    nms_all<<<dim3(1), dim3(THREADS), 0, stream>>>(boxes, scores, out);
}